// Round 7
// baseline (209.364 us; speedup 1.0000x reference)
//
#include <hip/hip_runtime.h>
#include <math.h>

#define MAXL 256
#define POS_BLOCKS 16
#define CMAX 8     // neg chunks (of 64 samples) buffered in registers per pass
#define TILE 256   // anchors per scan tile (LDS-staged)

// Workspace layout (header init'd in-kernel via init_flag barrier — no memset):
//   ws + 0  : int    pos_count (P)
//   ws + 4  : int    neg_count
//   ws + 8  : int    done1 (scan barrier)
//   ws + 12 : int    done2 (finalize)
//   ws + 16 : int    init_flag (atomicExch to 1; 0xAA poison != 1)
//   ws + 32 : double pos_loss
//   ws + 40 : double neg_loss
//   ws + 64 : PosRec records (compacted positive anchors)
struct __align__(16) PosRec {
    float t0, t1, t2, t3;
    int c2, h, w, pad;
};

__global__ void __launch_bounds__(256)
k_all(const float* __restrict__ anchor,
      const float* __restrict__ label,
      const float* __restrict__ cla,
      const float* __restrict__ reg,
      const int* __restrict__ neg,
      const int* __restrict__ dA,
      const int* __restrict__ dF,
      const int* __restrict__ dC,
      int N, int L, int B, int S, int maxRec,
      char* __restrict__ ws,
      float* __restrict__ out)
{
    int*    cnt       = (int*)(ws + 0);
    int*    neg_cnt   = (int*)(ws + 4);
    int*    done1     = (int*)(ws + 8);
    int*    done2     = (int*)(ws + 12);
    int*    init_flag = (int*)(ws + 16);
    double* pos_loss  = (double*)(ws + 32);
    double* neg_loss  = (double*)(ws + 40);
    PosRec* recs      = (PosRec*)(ws + 64);

    const int A  = *dA;
    const int F  = *dF;
    const float Cf = (float)(*dC);
    const size_t hw = (size_t)F * F;
    const int tid  = blockIdx.x * blockDim.x + threadIdx.x;
    const int lane = threadIdx.x & 63;

    __shared__ float sh_a[TILE * 7];   // 28 KB anchor tile
    __shared__ float sh_cls[MAXL];
    __shared__ int   sh_occ[MAXL];
    __shared__ int   shP;

    // ---- LDS label staging ----
    const bool useLds = (L <= MAXL);
    if (useLds) {
        for (int j = threadIdx.x; j < L; j += blockDim.x)
            sh_cls[j] = label[(size_t)j * 5];
        __syncthreads();
        for (int j = threadIdx.x; j < L; j += blockDim.x) {
            float c = sh_cls[j];
            int o = 0;
            for (int k = 0; k < j; ++k) o += (sh_cls[k] == c) ? 1 : 0;
            sh_occ[j] = o;
        }
        // (no syncthreads needed here; phase-0 barrier below syncs)
    }

    // ---- phase 0: init barrier (robust to any initial ws content) ----
    if (tid == 0) {
        *cnt = 0; *neg_cnt = 0; *done1 = 0; *done2 = 0;
        *pos_loss = 0.0; *neg_loss = 0.0;
        __threadfence();
        atomicExch(init_flag, 1);
    }
    if (threadIdx.x == 0) {
        while (atomicAdd(init_flag, 0) != 1) __builtin_amdgcn_s_sleep(8);
        __threadfence();
    }
    __syncthreads();

    // ---- phase 1: tiled, coalesced anchor scan; compact positives ----
    const int numTiles = (N + TILE - 1) / TILE;
    for (int tile = blockIdx.x; tile < numTiles; tile += gridDim.x) {
        int base = tile * TILE;
        int cntA = N - base; if (cntA > TILE) cntA = TILE;
        int nfl  = cntA * 7;
        int n4   = nfl >> 2;

        // coalesced float4 bulk copy (base*7 is a multiple of 4 since TILE*7%4==0)
        const float4* src = (const float4*)(anchor + (size_t)base * 7);
        float4* dst = (float4*)sh_a;
        for (int i = threadIdx.x; i < n4; i += blockDim.x) dst[i] = src[i];
        for (int i = (n4 << 2) + threadIdx.x; i < nfl; i += blockDim.x)
            sh_a[i] = anchor[(size_t)base * 7 + i];
        __syncthreads();

        if ((int)threadIdx.x < cntA) {
            const float* a = sh_a + threadIdx.x * 7;
            float albl = a[1];
            if (albl != -1.0f && albl != Cf) {
                float ax = a[2], ay = a[3], aw = a[4], ah = a[5], aocc = a[6];

                int gt = 0;   // first match; argmax(all-false)=0
                for (int j = 0; j < L; ++j) {
                    float cj; int oj;
                    if (useLds) { cj = sh_cls[j]; oj = sh_occ[j]; }
                    else {
                        cj = label[(size_t)j * 5];
                        oj = 0;
                        for (int k = 0; k < j; ++k)
                            oj += (label[(size_t)k * 5] == cj) ? 1 : 0;
                    }
                    if (cj == albl && (float)oj == aocc) { gt = j; break; }
                }
                const float* g = label + (size_t)gt * 5;

                int n = base + threadIdx.x;
                PosRec r;
                r.t0 = (g[1] - ax) / aw;
                r.t1 = (g[2] - ay) / ah;
                r.t2 = logf(g[3] / aw);
                r.t3 = logf(g[4] / ah);
                int tmp = n / A;
                int ai  = n - tmp * A;
                r.h = tmp % F;
                r.w = tmp / F;
                r.c2 = ai * 2;
                r.pad = 0;

                int slot = atomicAdd(cnt, 1);
                if (slot < maxRec) recs[slot] = r;
            }
        }
        __syncthreads();
    }

    // ---- barrier: all scan work visible device-wide ----
    if (threadIdx.x == 0) {
        __threadfence();
        atomicAdd(done1, 1);
        while (atomicAdd(done1, 0) < (int)gridDim.x) __builtin_amdgcn_s_sleep(8);
        __threadfence();
        shP = atomicAdd(cnt, 0);
    }
    __syncthreads();
    const int P = shP;

    // ---- phase 2 ----
    if (blockIdx.x < POS_BLOCKS) {
        // positive losses: P*B independent tasks
        const int ptid = blockIdx.x * blockDim.x + threadIdx.x;
        const int pnth = POS_BLOCKS * blockDim.x;
        int Pc = (P < maxRec) ? P : maxRec;
        const int T = Pc * B;

        double acc = 0.0;
        for (int task = ptid; task < T; task += pnth) {
            int p = task / B;
            int b = task - p * B;
            PosRec r = recs[p];
            int c4 = r.c2 * 2;

            size_t regBase = (((size_t)b * (4 * A) + c4) * F + r.h) * F + r.w;
            float d0 = reg[regBase]          - r.t0;
            float d1 = reg[regBase +     hw] - r.t1;
            float d2 = reg[regBase + 2 * hw] - r.t2;
            float d3 = reg[regBase + 3 * hw] - r.t3;

            float lr = 0.0f, ad;
            ad = fabsf(d0); lr += (ad < 1.0f) ? 0.5f * d0 * d0 : ad - 0.5f;
            ad = fabsf(d1); lr += (ad < 1.0f) ? 0.5f * d1 * d1 : ad - 0.5f;
            ad = fabsf(d2); lr += (ad < 1.0f) ? 0.5f * d2 * d2 : ad - 0.5f;
            ad = fabsf(d3); lr += (ad < 1.0f) ? 0.5f * d3 * d3 : ad - 0.5f;
            lr *= 0.25f;

            size_t claBase = (((size_t)b * (2 * A) + r.c2) * F + r.h) * F + r.w;
            float x0 = cla[claBase];
            float x1 = cla[claBase + hw];
            float m  = fmaxf(x0, x1);
            float lse = m + logf(expf(x0 - m) + expf(x1 - m));

            acc += (double)((lse - x1) + 4.0f * lr);
        }
        for (int off = 32; off > 0; off >>= 1) acc += __shfl_down(acc, off, 64);
        if (lane == 0 && acc != 0.0) atomicAdd(pos_loss, acc);
    } else if (blockIdx.x < POS_BLOCKS + ((B + 3) >> 2)) {
        // negatives: one wave per batch row, gathers parallelized
        int gwave = (blockIdx.x - POS_BLOCKS) * (blockDim.x >> 6) + (threadIdx.x >> 6);
        if (gwave < B) {
            int b = gwave;
            const int limit = 3 * P;
            const unsigned long long lanemask = (1ull << lane) - 1ull;

            int base = 0;
            float lsum = 0.0f;
            int lcnt = 0;

            for (int g0 = 0; g0 < S; g0 += 64 * CMAX) {
                int   idxr[CMAX];
                float lblr[CMAX];

                #pragma unroll
                for (int c = 0; c < CMAX; ++c) {
                    int s = g0 + c * 64 + lane;
                    idxr[c] = (s < S) ? neg[(size_t)b * S + s] : 0;
                }
                #pragma unroll
                for (int c = 0; c < CMAX; ++c) {
                    int s = g0 + c * 64 + lane;
                    lblr[c] = (s < S) ? anchor[(size_t)idxr[c] * 7 + 1] : -2.0f;
                }
                #pragma unroll
                for (int c = 0; c < CMAX; ++c) {
                    int s = g0 + c * 64 + lane;
                    bool valid = (s < S);
                    bool isneg = valid && (lblr[c] == Cf);
                    unsigned long long mask = __ballot(isneg);
                    int pre = __popcll(mask & lanemask);
                    int cum = base + pre + (isneg ? 1 : 0);   // inclusive cumsum
                    bool inc = isneg && (cum <= limit);
                    base += __popcll(mask);

                    int idx = idxr[c];
                    int tmp = idx / A;
                    int ai  = idx - tmp * A;
                    int h   = tmp % F;
                    int w2  = tmp / F;
                    size_t claBase = (((size_t)b * (2 * A) + ai * 2) * F + h) * F + w2;
                    float x0 = valid ? cla[claBase]      : 0.0f;
                    float x1 = valid ? cla[claBase + hw] : 0.0f;
                    float m  = fmaxf(x0, x1);
                    float l  = m + logf(expf(x0 - m) + expf(x1 - m)) - x0;
                    lsum += inc ? l : 0.0f;
                    lcnt += inc ? 1 : 0;
                }
            }
            for (int off = 32; off > 0; off >>= 1) {
                lsum += __shfl_down(lsum, off, 64);
                lcnt += __shfl_down(lcnt, off, 64);
            }
            if (lane == 0 && lcnt != 0) {
                atomicAdd(neg_loss, (double)lsum);
                atomicAdd(neg_cnt, lcnt);
            }
        }
    }

    // ---- phase 3: last block finalizes ----
    __syncthreads();
    if (threadIdx.x == 0) {
        __threadfence();
        int t = atomicAdd(done2, 1);
        if (t == (int)gridDim.x - 1) {
            __threadfence();
            double denom = (double)(B * P + atomicAdd(neg_cnt, 0));
            out[0] = (float)((*pos_loss + *neg_loss) / denom);
        }
    }
}

extern "C" void kernel_launch(void* const* d_in, const int* in_sizes, int n_in,
                              void* d_out, int out_size, void* d_ws, size_t ws_size,
                              hipStream_t stream) {
    const float* cla    = (const float*)d_in[0];
    const float* reg    = (const float*)d_in[1];
    const float* label  = (const float*)d_in[2];
    const float* anchor = (const float*)d_in[3];
    const int*   neg    = (const int*)d_in[4];
    const int*   dA     = (const int*)d_in[5];
    const int*   dF     = (const int*)d_in[6];
    const int*   dC     = (const int*)d_in[7];

    int N = in_sizes[3] / 7;           // A*F*F
    int L = in_sizes[2] / 5;           // num labels
    int B = in_sizes[0] / (2 * N);     // batch
    int S = in_sizes[4] / B;           // neg samples per batch

    char* ws = (char*)d_ws;
    int maxRec = (int)((ws_size - 64) / sizeof(PosRec));

    // 512 blocks x 256 threads, ~30.5 KB LDS each -> 2 blocks/CU on 256 CUs,
    // all co-resident, so the in-kernel spin barriers cannot deadlock.
    int grid = 512;
    int needed = POS_BLOCKS + (B + 3) / 4;
    if (grid < needed) grid = needed;

    k_all<<<grid, 256, 0, stream>>>(anchor, label, cla, reg, neg,
                                    dA, dF, dC, N, L, B, S, maxRec,
                                    ws, (float*)d_out);
}

// Round 8
// 155.168 us; speedup vs baseline: 1.3493x; 1.3493x over previous
//
#include <hip/hip_runtime.h>
#include <math.h>

#define MAXL 256
#define POS_BLOCKS 16
#define CMAX 8   // neg chunks (of 64 samples) buffered in registers per pass

// Workspace layout (first 64 bytes zeroed via hipMemsetAsync):
//   ws + 0  : int    pos_count (P)
//   ws + 4  : int    neg_count
//   ws + 8  : int    blocks_done
//   ws + 16 : double pos_loss
//   ws + 24 : double neg_loss
//   ws + 64 : PosRec records (compacted positive anchors)
struct __align__(16) PosRec {
    float t0, t1, t2, t3;
    int c2, h, w, pad;
};

// ---- Kernel 1: vectorized anchor scan; 4 anchors (7 float4s) per thread ----
__global__ void __launch_bounds__(256)
k_scan(const float* __restrict__ anchor,
       const float* __restrict__ label,
       const int* __restrict__ dA,
       const int* __restrict__ dF,
       const int* __restrict__ dC,
       int N, int L, int maxRec,
       int* __restrict__ cnt,
       PosRec* __restrict__ recs)
{
    const int A = *dA;
    const int F = *dF;
    const float Cf = (float)(*dC);

    __shared__ float sh_cls[MAXL];
    __shared__ int   sh_occ[MAXL];
    const bool useLds = (L <= MAXL);
    if (useLds) {
        for (int j = threadIdx.x; j < L; j += blockDim.x)
            sh_cls[j] = label[(size_t)j * 5];
        __syncthreads();
        for (int j = threadIdx.x; j < L; j += blockDim.x) {
            float c = sh_cls[j];
            int o = 0;
            for (int k = 0; k < j; ++k) o += (sh_cls[k] == c) ? 1 : 0;
            sh_occ[j] = o;
        }
        __syncthreads();
    }

    const int t = blockIdx.x * blockDim.x + threadIdx.x;
    const int base = t * 4;
    if (base >= N) return;

    // 4 anchors = 28 floats = 7 float4s; base*7*4B = 112*t bytes (16B-aligned).
    float f[28];
    if (base + 4 <= N) {
        const float4* src = (const float4*)(anchor + (size_t)base * 7);
        #pragma unroll
        for (int i = 0; i < 7; ++i) {
            float4 v = src[i];
            f[4 * i + 0] = v.x; f[4 * i + 1] = v.y;
            f[4 * i + 2] = v.z; f[4 * i + 3] = v.w;
        }
    } else {
        int rem = (N - base) * 7;
        for (int i = 0; i < rem; ++i) f[i] = anchor[(size_t)base * 7 + i];
    }

    #pragma unroll
    for (int j = 0; j < 4; ++j) {
        int n = base + j;
        if (n >= N) break;
        float albl = f[7 * j + 1];
        if (albl == -1.0f || albl == Cf) continue;

        float ax = f[7 * j + 2], ay = f[7 * j + 3];
        float aw = f[7 * j + 4], ah = f[7 * j + 5];
        float aocc = f[7 * j + 6];

        int gt = 0;   // first match; argmax(all-false)=0
        for (int jj = 0; jj < L; ++jj) {
            float cj; int oj;
            if (useLds) { cj = sh_cls[jj]; oj = sh_occ[jj]; }
            else {
                cj = label[(size_t)jj * 5];
                oj = 0;
                for (int k = 0; k < jj; ++k) oj += (label[(size_t)k * 5] == cj) ? 1 : 0;
            }
            if (cj == albl && (float)oj == aocc) { gt = jj; break; }
        }
        const float* g = label + (size_t)gt * 5;

        PosRec r;
        r.t0 = (g[1] - ax) / aw;
        r.t1 = (g[2] - ay) / ah;
        r.t2 = logf(g[3] / aw);
        r.t3 = logf(g[4] / ah);
        int tmp = n / A;
        int ai  = n - tmp * A;
        r.h = tmp % F;
        r.w = tmp / F;
        r.c2 = ai * 2;
        r.pad = 0;

        int slot = atomicAdd(cnt, 1);
        if (slot < maxRec) recs[slot] = r;
    }
}

// ---- Kernel 2: fused pos + neg + finalize (last-block-done) ----
__global__ void __launch_bounds__(256)
k_loss(const float* __restrict__ cla,
       const float* __restrict__ reg,
       const float* __restrict__ anchor,
       const int* __restrict__ neg,
       const int* __restrict__ dA,
       const int* __restrict__ dF,
       const int* __restrict__ dC,
       int B, int S, int maxRec,
       int* __restrict__ cnt,
       const PosRec* __restrict__ recs,
       double* __restrict__ pos_loss,
       double* __restrict__ neg_loss,
       int* __restrict__ neg_cnt,
       int* __restrict__ done,
       float* __restrict__ out)
{
    const int A = *dA;
    const int F = *dF;
    const size_t hw = (size_t)F * F;
    const int P = *cnt;
    const int lane = threadIdx.x & 63;

    if (blockIdx.x < POS_BLOCKS) {
        // -------- positive losses: P*B independent tasks --------
        const int tid = blockIdx.x * blockDim.x + threadIdx.x;
        const int nth = POS_BLOCKS * blockDim.x;
        int Pc = (P < maxRec) ? P : maxRec;
        const int T = Pc * B;

        double acc = 0.0;
        for (int task = tid; task < T; task += nth) {
            int p = task / B;
            int b = task - p * B;
            PosRec r = recs[p];
            int c4 = r.c2 * 2;

            size_t regBase = (((size_t)b * (4 * A) + c4) * F + r.h) * F + r.w;
            float d0 = reg[regBase]          - r.t0;
            float d1 = reg[regBase +     hw] - r.t1;
            float d2 = reg[regBase + 2 * hw] - r.t2;
            float d3 = reg[regBase + 3 * hw] - r.t3;

            float lr = 0.0f, ad;
            ad = fabsf(d0); lr += (ad < 1.0f) ? 0.5f * d0 * d0 : ad - 0.5f;
            ad = fabsf(d1); lr += (ad < 1.0f) ? 0.5f * d1 * d1 : ad - 0.5f;
            ad = fabsf(d2); lr += (ad < 1.0f) ? 0.5f * d2 * d2 : ad - 0.5f;
            ad = fabsf(d3); lr += (ad < 1.0f) ? 0.5f * d3 * d3 : ad - 0.5f;
            lr *= 0.25f;

            size_t claBase = (((size_t)b * (2 * A) + r.c2) * F + r.h) * F + r.w;
            float x0 = cla[claBase];
            float x1 = cla[claBase + hw];
            float m  = fmaxf(x0, x1);
            float lse = m + logf(expf(x0 - m) + expf(x1 - m));

            acc += (double)((lse - x1) + 4.0f * lr);
        }
        for (int off = 32; off > 0; off >>= 1) acc += __shfl_down(acc, off, 64);
        if (lane == 0 && acc != 0.0) atomicAdd(pos_loss, acc);
    } else {
        // -------- negatives: one wave per batch row, gathers parallelized --------
        const float Cf = (float)(*dC);
        int gwave = (blockIdx.x - POS_BLOCKS) * (blockDim.x >> 6) + (threadIdx.x >> 6);
        if (gwave < B) {
            int b = gwave;
            const int limit = 3 * P;
            const unsigned long long lanemask = (1ull << lane) - 1ull;

            int base = 0;
            float lsum = 0.0f;
            int lcnt = 0;

            for (int g0 = 0; g0 < S; g0 += 64 * CMAX) {
                int   idxr[CMAX];
                float lblr[CMAX];

                #pragma unroll
                for (int c = 0; c < CMAX; ++c) {
                    int s = g0 + c * 64 + lane;
                    idxr[c] = (s < S) ? neg[(size_t)b * S + s] : 0;
                }
                #pragma unroll
                for (int c = 0; c < CMAX; ++c) {
                    int s = g0 + c * 64 + lane;
                    lblr[c] = (s < S) ? anchor[(size_t)idxr[c] * 7 + 1] : -2.0f;
                }
                #pragma unroll
                for (int c = 0; c < CMAX; ++c) {
                    int s = g0 + c * 64 + lane;
                    bool valid = (s < S);
                    bool isneg = valid && (lblr[c] == Cf);
                    unsigned long long mask = __ballot(isneg);
                    int pre = __popcll(mask & lanemask);
                    int cum = base + pre + (isneg ? 1 : 0);   // inclusive cumsum
                    bool inc = isneg && (cum <= limit);
                    base += __popcll(mask);

                    int idx = idxr[c];
                    int tmp = idx / A;
                    int ai  = idx - tmp * A;
                    int h   = tmp % F;
                    int w2  = tmp / F;
                    size_t claBase = (((size_t)b * (2 * A) + ai * 2) * F + h) * F + w2;
                    float x0 = valid ? cla[claBase]      : 0.0f;
                    float x1 = valid ? cla[claBase + hw] : 0.0f;
                    float m  = fmaxf(x0, x1);
                    float l  = m + logf(expf(x0 - m) + expf(x1 - m)) - x0;
                    lsum += inc ? l : 0.0f;
                    lcnt += inc ? 1 : 0;
                }
            }
            for (int off = 32; off > 0; off >>= 1) {
                lsum += __shfl_down(lsum, off, 64);
                lcnt += __shfl_down(lcnt, off, 64);
            }
            if (lane == 0 && lcnt != 0) {
                atomicAdd(neg_loss, (double)lsum);
                atomicAdd(neg_cnt, lcnt);
            }
        }
    }

    // -------- finalize: last block to finish writes the output --------
    __syncthreads();
    if (threadIdx.x == 0) {
        __threadfence();
        int t = atomicAdd(done, 1);
        if (t == (int)gridDim.x - 1) {
            __threadfence();
            double denom = (double)(B * P + *neg_cnt);
            out[0] = (float)((*pos_loss + *neg_loss) / denom);
        }
    }
}

extern "C" void kernel_launch(void* const* d_in, const int* in_sizes, int n_in,
                              void* d_out, int out_size, void* d_ws, size_t ws_size,
                              hipStream_t stream) {
    const float* cla    = (const float*)d_in[0];
    const float* reg    = (const float*)d_in[1];
    const float* label  = (const float*)d_in[2];
    const float* anchor = (const float*)d_in[3];
    const int*   neg    = (const int*)d_in[4];
    const int*   dA     = (const int*)d_in[5];
    const int*   dF     = (const int*)d_in[6];
    const int*   dC     = (const int*)d_in[7];

    int N = in_sizes[3] / 7;           // A*F*F
    int L = in_sizes[2] / 5;           // num labels
    int B = in_sizes[0] / (2 * N);     // batch
    int S = in_sizes[4] / B;           // neg samples per batch

    char* ws = (char*)d_ws;
    int*    cnt      = (int*)(ws + 0);
    int*    neg_cnt  = (int*)(ws + 4);
    int*    done     = (int*)(ws + 8);
    double* pos_loss = (double*)(ws + 16);
    double* neg_loss = (double*)(ws + 24);
    PosRec* recs     = (PosRec*)(ws + 64);
    int maxRec = (int)((ws_size - 64) / sizeof(PosRec));

    hipMemsetAsync(ws, 0, 64, stream);

    // 4 anchors per thread, fully vectorized float4 loads.
    int threads_needed = (N + 3) / 4;
    int scanGrid = (threads_needed + 255) / 256;
    k_scan<<<scanGrid, 256, 0, stream>>>(anchor, label, dA, dF, dC,
                                         N, L, maxRec, cnt, recs);

    int negBlocks = (B + 3) / 4;              // 4 waves per 256-thread block
    int lossGrid = POS_BLOCKS + negBlocks;
    k_loss<<<lossGrid, 256, 0, stream>>>(cla, reg, anchor, neg, dA, dF, dC,
                                         B, S, maxRec, cnt, recs,
                                         pos_loss, neg_loss, neg_cnt, done,
                                         (float*)d_out);
}